// Round 1
// 189.675 us; speedup vs baseline: 1.0361x; 1.0361x over previous
//
#include <hip/hip_runtime.h>
#include <cstdint>
#include <cstddef>

// MultiHeadAttention R11:
//   cast -> NEW 256x256-tile 8-wave phase-split MFMA QKV GEMM (m201-style:
//   BK=64, 2-deep LDS dbuf, 4 phases/K-tile, ONE counted vmcnt(4)/K-tile,
//   st_16x32 XOR swizzle via pre-swizzled global source + swizzled ds_read,
//   setprio around MFMA clusters) ->
//   MFMA flash attention (unchanged R8/R10 structure) ->
//   MFMA out-proj (unchanged 128^2 triple-buffered kernel).
// ws layout (bytes):
//   xb @0 [4096][1024] bf16 | wqb @8388608 [3072][1024] | wob @14680064 [1024][1024]
//   Qb @16777216, Kb @25165824: [2][16][2048][64] bf16 (Qb = Q*log2e)
//   Vt @33554432: [2][16][64][2048] bf16 (transposed)
//   CTX @41943040 [4096][1024] bf16
// MFMA 16x16x32_bf16 frags: A[m=lane&15][k=quad*8+i], B[n=lane&15][k=quad*8+i],
// C/D[row=quad*4+reg][col=lane&15]. Swapped operands -> D = C^T.

typedef __attribute__((ext_vector_type(8))) short bf16x8;
typedef __attribute__((ext_vector_type(4))) float f32x4;

#define LOG2E 1.44269504f

#define MFMA16(a, b, c) __builtin_amdgcn_mfma_f32_16x16x32_bf16((a), (b), (c), 0, 0, 0)

#define GLDS16(g, s)                                                        \
  __builtin_amdgcn_global_load_lds(                                         \
      (const __attribute__((address_space(1))) void*)(g),                   \
      (__attribute__((address_space(3))) void*)(s), 16, 0, 0)

// Manual barrier: wait until <= N vector-memory ops outstanding, then barrier.
// ONLY valid when the loop's vmem traffic is exclusively the staged GLDS.
#define ASYNC_BAR(N) asm volatile("s_waitcnt vmcnt(" #N ")\n\ts_barrier" ::: "memory")
#define BAR() asm volatile("s_barrier" ::: "memory")

#if __has_builtin(__builtin_amdgcn_exp2f)
#define EXP2F(x) __builtin_amdgcn_exp2f(x)
#else
#define EXP2F(x) exp2f(x)
#endif

static __device__ __forceinline__ unsigned short f2bf(float f) {  // RNE
  unsigned int u = __builtin_bit_cast(unsigned int, f);
  u += 0x7FFFu + ((u >> 16) & 1u);
  return (unsigned short)(u >> 16);
}

// pack two fp32 -> two bf16 (round-nearest) in one u32: 2 add + 1 perm
static __device__ __forceinline__ unsigned int pk2bf(float a, float b) {
  const unsigned int ua = __builtin_bit_cast(unsigned int, a) + 0x8000u;
  const unsigned int ub = __builtin_bit_cast(unsigned int, b) + 0x8000u;
  return __builtin_amdgcn_perm(ub, ua, 0x07060302);
}

// ---------------------------------------------------------------------------
__global__ __launch_bounds__(256) void cast_bf16(const float* __restrict__ x,
                                                 const float* __restrict__ wq,
                                                 const float* __restrict__ wo,
                                                 unsigned short* __restrict__ xb,
                                                 unsigned short* __restrict__ wqb,
                                                 unsigned short* __restrict__ wob)
{
  const int id = blockIdx.x * 256 + threadIdx.x;
  const float* src;
  unsigned short* dst;
  int off;
  if (id < 1048576)               { src = x;  dst = xb;  off = id; }
  else if (id < 1048576 + 786432) { src = wq; dst = wqb; off = id - 1048576; }
  else                            { src = wo; dst = wob; off = id - (1048576 + 786432); }
  float4 v = ((const float4*)src)[off];
  ushort4 o;
  o.x = f2bf(v.x); o.y = f2bf(v.y); o.z = f2bf(v.z); o.w = f2bf(v.w);
  ((ushort4*)dst)[off] = o;
}

// ---------------------------------------------------------------------------
// QKV GEMM R11: 256x256 tile, BK=64, 512 threads = 8 waves (2M x 4N),
// per-wave 128x64 output (acc[8][4] of 16x16 frags).
// LDS 128 KiB: 2 buffers x (A 256x64 | B 256x64) bf16, rows of 128B split
// into 8x16B slots, phys_slot = logical_slot ^ (((row>>2)&1)<<1)  (st_16x32).
// global_load_lds writes linearly -> the GLOBAL source is pre-swizzled
// (same involution), ds_reads apply the swizzle on the read side.
// 4 phases per K-tile (quadrants: (msub,nsub) = 00,01,11,10), 16 MFMA each.
// Staging: 1 half-tile (2 GLDS/thread) per phase, 1.25 tiles ahead:
//   t-P0: B-hi(t+1) | t-P1: A-hi(t+1) | t-P2: B-lo(t+2) | t-P3: A-lo(t+2)
// ONE vmcnt(4) per K-tile (at P0) -- loads never drained in-loop.
// Barriers at P0 (with vmcnt), P2, P3; P0->P1 needs none (disjoint buffers).
// K order identical to R10 -> bitwise-identical accumulation.
// ---------------------------------------------------------------------------
#define MMAC(AF, BF, MS, NS)                                                       \
  do {                                                                             \
    __builtin_amdgcn_s_setprio(1);                                                 \
    if (swapped) {                                                                 \
      _Pragma("unroll")                                                            \
      for (int mt = 0; mt < 4; ++mt)                                               \
        _Pragma("unroll")                                                          \
        for (int nt = 0; nt < 2; ++nt) {                                           \
          acc[(MS)*4+mt][(NS)*2+nt] = MFMA16(BF[nt][0], AF[mt][0], acc[(MS)*4+mt][(NS)*2+nt]); \
          acc[(MS)*4+mt][(NS)*2+nt] = MFMA16(BF[nt][1], AF[mt][1], acc[(MS)*4+mt][(NS)*2+nt]); \
        }                                                                          \
    } else {                                                                       \
      _Pragma("unroll")                                                            \
      for (int mt = 0; mt < 4; ++mt)                                               \
        _Pragma("unroll")                                                          \
        for (int nt = 0; nt < 2; ++nt) {                                           \
          acc[(MS)*4+mt][(NS)*2+nt] = MFMA16(AF[mt][0], BF[nt][0], acc[(MS)*4+mt][(NS)*2+nt]); \
          acc[(MS)*4+mt][(NS)*2+nt] = MFMA16(AF[mt][1], BF[nt][1], acc[(MS)*4+mt][(NS)*2+nt]); \
        }                                                                          \
    }                                                                              \
    __builtin_amdgcn_s_setprio(0);                                                 \
  } while (0)

__global__ __launch_bounds__(512, 2) void gemm_qkv(const unsigned short* __restrict__ A,
                                                   const unsigned short* __restrict__ B,
                                                   unsigned short* __restrict__ Qb,
                                                   unsigned short* __restrict__ Kb,
                                                   unsigned short* __restrict__ Vt)
{
  // shorts: buf b: A @ b*32768 (256 rows x 64), B @ b*32768+16384. 128 KiB.
  __shared__ unsigned short pool[65536];

  const int tid  = threadIdx.x;
  const int wave = tid >> 6, lane = tid & 63, quad = lane >> 4, cl = lane & 15;
  const int wm = wave >> 2, wn = wave & 3;

  // Bijective XCD chunking: 192 blocks, 24/XCD covering a 4(mb) x 6(nb) chunk.
  const int bid = blockIdx.x;
  const int xcd = bid & 7, j = bid >> 3;
  const int mb = (xcd >> 1) * 4 + j / 6;
  const int nb = (xcd & 1) * 6 + j % 6;
  const int m0 = mb * 256, n0 = nb * 256;
  const int part = nb >> 2;                 // 0=Q 1=K 2=V
  const bool swapped = (part < 2);

  // --- staging: per GLDS16, wave covers 8 rows x 128B linearly.
  // lane l -> row r0+(l>>3), phys slot l&7; source logical slot pre-swizzled:
  const int lrow = lane >> 3;
  const int sg   = (lane & 7) ^ (((lane >> 5) & 1) << 1);   // (row>>2)&1 == (l>>5)&1

  auto stageA = [&](int h0, int buf, int k0) {
    #pragma unroll
    for (int ii = 0; ii < 2; ++ii) {
      const int r0 = h0 + wave * 16 + ii * 8;
      GLDS16(A + (size_t)(m0 + r0 + lrow) * 1024 + k0 + sg * 8,
             &pool[buf * 32768 + r0 * 64]);
    }
  };
  auto stageB = [&](int h0, int buf, int k0) {
    #pragma unroll
    for (int ii = 0; ii < 2; ++ii) {
      const int r0 = h0 + wave * 16 + ii * 8;
      GLDS16(B + (size_t)(n0 + r0 + lrow) * 1024 + k0 + sg * 8,
             &pool[buf * 32768 + 16384 + r0 * 64]);
    }
  };

  // --- fragment reads (swizzled): row_l multiple-of-16 base + cl
  const int rswz = ((cl >> 2) & 1) << 1;
  auto loadA = [&](bf16x8 (&af)[4][2], int msub, int b) {
    const unsigned short* base = &pool[b * 32768];
    #pragma unroll
    for (int mt = 0; mt < 4; ++mt) {
      const int row = wm * 128 + msub * 64 + mt * 16 + cl;
      #pragma unroll
      for (int kk = 0; kk < 2; ++kk)
        af[mt][kk] = *(const bf16x8*)&base[row * 64 + ((kk * 4 + quad) ^ rswz) * 8];
    }
  };
  auto loadB = [&](bf16x8 (&bf)[2][2], int nsub, int b) {
    const unsigned short* base = &pool[b * 32768 + 16384];
    #pragma unroll
    for (int nt = 0; nt < 2; ++nt) {
      const int row = wn * 64 + nsub * 32 + nt * 16 + cl;
      #pragma unroll
      for (int kk = 0; kk < 2; ++kk)
        bf[nt][kk] = *(const bf16x8*)&base[row * 64 + ((kk * 4 + quad) ^ rswz) * 8];
    }
  };

  f32x4 acc[8][4];
  #pragma unroll
  for (int i = 0; i < 8; ++i)
    #pragma unroll
    for (int jj = 0; jj < 4; ++jj)
      #pragma unroll
      for (int r = 0; r < 4; ++r) acc[i][jj][r] = 0.f;

  // Prologue: all 4 half-tiles of tile0, then lo halves of tile1 (12 loads).
  stageB(0,   0, 0);
  stageA(0,   0, 0);
  stageB(128, 0, 0);
  stageA(128, 0, 0);
  stageB(0,   1, 64);
  stageA(0,   1, 64);

  #pragma unroll 1
  for (int t = 0; t < 16; ++t) {
    const int b = t & 1, bn = b ^ 1;
    const int kc  = (t + 1) * 64;
    const int kc2 = (t + 2) * 64;

    bf16x8 af[4][2], bfA[2][2], bfB[2][2];

    // P0: quadrant (0,0). vmcnt(4): guarantees all 4 halves of tile t
    // (newest needed = A-hi(t) @ (t-1)-P1; newer in flight = B-lo/A-lo(t+1)).
    if (t < 15) { ASYNC_BAR(4); } else { ASYNC_BAR(0); }
    loadA(af, 0, b);
    loadB(bfA, 0, b);
    if (t < 15) stageB(128, bn, kc);       // B-hi(t+1)
    MMAC(af, bfA, 0, 0);

    // P1: quadrant (0,1). No barrier needed: reads tile-t B (published at P0),
    // GLDS writes buffer bn (not being read).
    loadB(bfB, 1, b);
    if (t < 15) stageA(128, bn, kc);       // A-hi(t+1)
    MMAC(af, bfB, 0, 1);

    // P2: quadrant (1,1). Barrier: B-lo(t+2) overwrites B-lo(b) whose last
    // reads were P1 (other waves).
    BAR();
    loadA(af, 1, b);
    if (t < 14) stageB(0, b, kc2);         // B-lo(t+2)
    MMAC(af, bfB, 1, 1);

    // P3: quadrant (1,0), reuses bfA regs. Barrier: A-lo(t+2) overwrites
    // A-lo(b) whose last reads were P2 (wm=0 waves).
    BAR();
    if (t < 14) stageA(0, b, kc2);         // A-lo(t+2)
    MMAC(af, bfA, 1, 0);
  }
  // ASYNC_BAR(0) at t=15-P0 drained all staging: no GLDS in flight here.

  const int bb = m0 >> 11, ss = m0 & 2047;
  if (part < 2) {
    // Q/K (swapped: D=C^T): lane holds 4 consecutive d for one s -> ushort4
    unsigned short* dst = (part == 0) ? Qb : Kb;
    const float sc2 = (part == 0) ? LOG2E : 1.0f;
    const int npb = (n0 & 1023) + wn * 64;
    #pragma unroll
    for (int mt = 0; mt < 8; ++mt) {
      const int m = ss + wm * 128 + mt * 16 + cl;
      #pragma unroll
      for (int nt = 0; nt < 4; ++nt) {
        const int np = npb + nt * 16 + quad * 4;
        const int hh = np >> 6, d0 = np & 63;
        ushort4 pk;
        pk.x = f2bf(acc[mt][nt][0] * sc2);
        pk.y = f2bf(acc[mt][nt][1] * sc2);
        pk.z = f2bf(acc[mt][nt][2] * sc2);
        pk.w = f2bf(acc[mt][nt][3] * sc2);
        *(ushort4*)&dst[((size_t)(bb * 16 + hh) * 2048 + m) * 64 + d0] = pk;
      }
    }
  } else {
    // V (normal orientation): transpose through LDS (reuse pool),
    // trans[128][264] shorts per round; 2 rounds (wn pairs).
    unsigned short* trans = pool;
    #pragma unroll 1
    for (int r = 0; r < 2; ++r) {
      __syncthreads();
      if ((wn >> 1) == r) {
        #pragma unroll
        for (int mt = 0; mt < 8; ++mt) {
          const int s_l = wm * 128 + mt * 16 + quad * 4;
          #pragma unroll
          for (int nt = 0; nt < 4; ++nt) {
            const int n_l = (wn & 1) * 64 + nt * 16 + cl;
            ushort4 pk;
            pk.x = f2bf(acc[mt][nt][0]); pk.y = f2bf(acc[mt][nt][1]);
            pk.z = f2bf(acc[mt][nt][2]); pk.w = f2bf(acc[mt][nt][3]);
            *(ushort4*)&trans[n_l * 264 + s_l] = pk;
          }
        }
      }
      __syncthreads();
      const int row = tid >> 2, q4 = tid & 3;
      const int nv = (n0 & 1023) + r * 128 + row;
      const int hh = nv >> 6, d = nv & 63;
      unsigned short* drow = Vt + ((size_t)(bb * 16 + hh) * 64 + d) * 2048 + ss + q4 * 64;
      #pragma unroll
      for (int i = 0; i < 8; ++i)
        *(bf16x8*)(drow + i * 8) = *(const bf16x8*)&trans[row * 264 + q4 * 64 + i * 8];
    }
  }
}

// ---------------------------------------------------------------------------
// MFMA GEMM, TRIPLE-buffered K-loop, manual barriers (prefetch distance 2).
// Retained for the out-projection (MODE 0) only.
// ---------------------------------------------------------------------------
template <int MODE>
__global__ __launch_bounds__(256) void gemm_bt(const unsigned short* __restrict__ A,
                                               const unsigned short* __restrict__ B,
                                               const float* __restrict__ bias,
                                               float* __restrict__ OutF,
                                               unsigned short* __restrict__ Qb,
                                               unsigned short* __restrict__ Kb,
                                               unsigned short* __restrict__ Vt)
{
  __shared__ unsigned short pool[24576];   // 3 stages x (A 4096 | B 4096) shorts

  const int tid  = threadIdx.x;
  const int wave = tid >> 6, lane = tid & 63, quad = lane >> 4, cl = lane & 15;
  const int wm = wave >> 1, wn = wave & 1;
  const int m0 = blockIdx.y * 128, n0 = blockIdx.x * 128;
  const int sr = lane >> 2, sc = lane & 3;

  const int part = (MODE == 1) ? (n0 >> 10) : 0;     // 0=Q 1=K 2=V
  const bool swapped = (MODE == 0) || (part < 2);

  f32x4 acc[4][4];
  #pragma unroll
  for (int i = 0; i < 4; ++i)
    #pragma unroll
    for (int j = 0; j < 4; ++j)
      #pragma unroll
      for (int r = 0; r < 4; ++r) acc[i][j][r] = 0.f;

  const int scs = (sc ^ ((sr >> 1) & 3)) * 8;
  const int rchunk = (quad ^ ((cl >> 1) & 3)) * 8;

  auto stage = [&](int k0, int buf) {
    unsigned short* As = pool + buf * 8192;
    unsigned short* Bs = As + 4096;
    #pragma unroll
    for (int ii = 0; ii < 2; ++ii) {
      const int r = wave * 32 + ii * 16 + sr;
      GLDS16(A + (size_t)(m0 + r) * 1024 + k0 + scs, &As[(wave * 32 + ii * 16) * 32]);
      GLDS16(B + (size_t)(n0 + r) * 1024 + k0 + scs, &Bs[(wave * 32 + ii * 16) * 32]);
    }
  };

  stage(0, 0);
  stage(32, 1);
  int cur = 0;
  #pragma unroll 1
  for (int it = 0; it < 32; ++it) {
    if (it + 2 < 32) {
      ASYNC_BAR(4);                              // drain stage(it); keep stage(it+1)
      const int bnx = (cur == 0) ? 2 : cur - 1;  // (cur+2)%3
      stage((it + 2) * 32, bnx);
    } else if (it + 1 < 32) {
      ASYNC_BAR(4);
    } else {
      ASYNC_BAR(0);
    }

    const unsigned short* As = pool + cur * 8192;
    const unsigned short* Bs = As + 4096;
    bf16x8 af[4], bfr[4];
    #pragma unroll
    for (int mt = 0; mt < 4; ++mt)
      af[mt] = *(const bf16x8*)&As[(wm * 64 + mt * 16 + cl) * 32 + rchunk];
    #pragma unroll
    for (int nt = 0; nt < 4; ++nt)
      bfr[nt] = *(const bf16x8*)&Bs[(wn * 64 + nt * 16 + cl) * 32 + rchunk];

    if (swapped) {
      #pragma unroll
      for (int mt = 0; mt < 4; ++mt)
        #pragma unroll
        for (int nt = 0; nt < 4; ++nt)
          acc[mt][nt] = MFMA16(bfr[nt], af[mt], acc[mt][nt]);   // D = C^T
    } else {
      #pragma unroll
      for (int mt = 0; mt < 4; ++mt)
        #pragma unroll
        for (int nt = 0; nt < 4; ++nt)
          acc[mt][nt] = MFMA16(af[mt], bfr[nt], acc[mt][nt]);
    }
    cur = (cur == 2) ? 0 : cur + 1;
  }

  if (MODE == 1) {
    const int bb = m0 >> 11, ss = m0 & 2047;
    if (part == 2) {
      // V (normal orientation): transpose through LDS, coalesced Vt row stores
      #pragma unroll
      for (int half = 0; half < 2; ++half) {
        __syncthreads();
        if (wn == half) {
          #pragma unroll
          for (int mt = 0; mt < 4; ++mt)
            #pragma unroll
            for (int nt = 0; nt < 4; ++nt) {
              const int nl = nt * 16 + cl;
              const int ml = wm * 64 + mt * 16 + quad * 4;
              ushort4 pk;
              pk.x = f2bf(acc[mt][nt][0]); pk.y = f2bf(acc[mt][nt][1]);
              pk.z = f2bf(acc[mt][nt][2]); pk.w = f2bf(acc[mt][nt][3]);
              *(ushort4*)&pool[nl * 136 + ml] = pk;
            }
        }
        __syncthreads();
        const int row = tid >> 2, q4 = tid & 3;
        const int nglob = n0 + half * 64 + row;
        const int hh = (nglob >> 6) & 15, d = nglob & 63;
        unsigned short* drow = Vt + ((size_t)(bb * 16 + hh) * 64 + d) * 2048 + ss;
        #pragma unroll
        for (int i = 0; i < 4; ++i) {
          const bf16x8 v = *(const bf16x8*)&pool[row * 136 + q4 * 32 + i * 8];
          *(bf16x8*)(drow + q4 * 32 + i * 8) = v;
        }
      }
    } else {
      // Q/K (swapped: D=C^T): lane holds 4 consecutive d for one s -> ushort4
      unsigned short* dst = (part == 0) ? Qb : Kb;
      const float sc2 = (part == 0) ? LOG2E : 1.0f;
      #pragma unroll
      for (int mt = 0; mt < 4; ++mt) {
        const int m = ss + wm * 64 + mt * 16 + cl;
        #pragma unroll
        for (int nt = 0; nt < 4; ++nt) {
          const int np = (n0 & 1023) + wn * 64 + nt * 16 + quad * 4;
          const int hh = np >> 6, d0 = np & 63;
          ushort4 pk;
          pk.x = f2bf(acc[mt][nt][0] * sc2);
          pk.y = f2bf(acc[mt][nt][1] * sc2);
          pk.z = f2bf(acc[mt][nt][2] * sc2);
          pk.w = f2bf(acc[mt][nt][3] * sc2);
          *(ushort4*)&dst[((size_t)(bb * 16 + hh) * 2048 + m) * 64 + d0] = pk;
        }
      }
    }
  } else {
    #pragma unroll
    for (int mt = 0; mt < 4; ++mt) {
      const int m = m0 + wm * 64 + mt * 16 + cl;
      #pragma unroll
      for (int nt = 0; nt < 4; ++nt) {
        const int n = n0 + wn * 64 + nt * 16 + quad * 4;
        const float4 bv = *(const float4*)(bias + n);
        float4 o;
        o.x = acc[mt][nt][0] + bv.x; o.y = acc[mt][nt][1] + bv.y;
        o.z = acc[mt][nt][2] + bv.z; o.w = acc[mt][nt][3] + bv.w;
        *(float4*)&OutF[(size_t)m * 1024 + n] = o;
      }
    }
  }
}

// ---------------------------------------------------------------------------
// Flash attention R10 (unchanged): K AND V staged in LDS via GLDS with
// triple-buffered staging + manual vmcnt(4) barriers. Uniform blocks (wave
// owns low group g and high 127-g); no-max softmax P = 2^(q·k·log2e).
// ---------------------------------------------------------------------------
__global__ __launch_bounds__(256) void attn_mfma(const unsigned short* __restrict__ Qb,
                                                 const unsigned short* __restrict__ Kb,
                                                 const unsigned short* __restrict__ Vt,
                                                 unsigned short* __restrict__ CTX)
{
  __shared__ unsigned short Ksm[3][64 * 64];
  __shared__ unsigned short Vsm[3][64 * 64];
  __shared__ unsigned short Psm[4][32 * 40];

  const int tid  = threadIdx.x;
  const int wave = tid >> 6, lane = tid & 63, quad = lane >> 4, cl = lane & 15;

  const int L  = blockIdx.x;
  const int bh = 4 * (L & 7) + ((L >> 3) & 3);    // XCD-affine: 4 bh per XCD
  const int b  = bh >> 4, h = bh & 15;
  const int p  = L >> 5;                          // 0..15
  const int g  = p * 4 + wave;                    // low group 0..63
  const int qlo = g * 16;
  const int qhi = (127 - g) * 16;
  const size_t base = (size_t)bh * (2048 * 64);

  bf16x8 qf[2][2];
  #pragma unroll
  for (int dk = 0; dk < 2; ++dk) {
    qf[0][dk] = *(const bf16x8*)(Qb + base + (size_t)(qlo + cl) * 64 + dk * 32 + quad * 8);
    qf[1][dk] = *(const bf16x8*)(Qb + base + (size_t)(qhi + cl) * 64 + dk * 32 + quad * 8);
  }

  f32x4 oacc[2][4];
  #pragma unroll
  for (int mf = 0; mf < 2; ++mf)
    #pragma unroll
    for (int dt = 0; dt < 4; ++dt)
      #pragma unroll
      for (int r = 0; r < 4; ++r) oacc[mf][dt][r] = 0.f;
  float lr[2][4] = {};

  bf16x8 ones;
  #pragma unroll
  for (int k = 0; k < 8; ++k) ones[k] = (short)0x3F80;

  const int lrow  = lane >> 3;
  const int lslot = (lane & 7) ^ lrow;
  const int nch = 32 - p;                          // >= 17

  auto stageKV = [&](int j64, int buf) {
    #pragma unroll
    for (int ii = 0; ii < 2; ++ii) {
      const int r0 = wave * 16 + ii * 8;
      GLDS16(Kb + base + (size_t)(j64 + r0 + lrow) * 64 + lslot * 8, &Ksm[buf][r0 * 64]);
      GLDS16(Vt + base + (size_t)(r0 + lrow) * 2048 + j64 + lslot * 8, &Vsm[buf][r0 * 64]);
    }
  };

  stageKV(0, 0);
  stageKV(64, 1);
  int cur = 0;
  #pragma unroll 1
  for (int ch = 0; ch < nch; ++ch) {
    if (ch + 2 < nch) {
      ASYNC_BAR(4);                              // drain stage(ch); keep stage(ch+1)
      const int bnx = (cur == 0) ? 2 : cur - 1;
      stageKV((ch + 2) * 64, bnx);
    } else if (ch + 1 < nch) {
      ASYNC_BAR(4);
    } else {
      ASYNC_BAR(0);
    }

    const int j64 = ch * 64;
    #pragma unroll
    for (int jli = 0; jli < 2; ++jli) {
      const int jg0 = j64 + jli * 32;
      if (jg0 > qhi + 15) continue;
      const bool lowAct = (jg0 <= qlo + 15);
      const int jl = jli * 32;

      bf16x8 kf[2][2];
      #pragma unroll
      for (int jf = 0; jf < 2; ++jf)
        #pragma unroll
        for (int dk = 0; dk < 2; ++dk) {
          const int jrow = jl + jf * 16 + cl;
          const int slot = (dk * 4 + quad) ^ (cl & 7);
          kf[jf][dk] = *(const bf16x8*)&Ksm[cur][jrow * 64 + slot * 8];
        }

      f32x4 st[2][2];
      #pragma unroll
      for (int jf = 0; jf < 2; ++jf)
        #pragma unroll
        for (int mf = 0; mf < 2; ++mf) {
          if (mf == 0 && !lowAct) continue;
          f32x4 z;
          #pragma unroll
          for (int r = 0; r < 4; ++r) z[r] = 0.f;
          z = MFMA16(kf[jf][0], qf[mf][0], z);
          st[jf][mf] = MFMA16(kf[jf][1], qf[mf][1], z);
        }

      #pragma unroll
      for (int mf = 0; mf < 2; ++mf) {
        if (mf == 0 && !lowAct) continue;
        const int qbase = mf ? qhi : qlo;
        const bool diag = (jg0 + 32 > qbase);
        #pragma unroll
        for (int jf = 0; jf < 2; ++jf) {
          float pv[4];
          if (diag) {
            const int qg = qbase + cl;
            #pragma unroll
            for (int r = 0; r < 4; ++r) {
              const int jg = jg0 + jf * 16 + quad * 4 + r;
              pv[r] = (jg <= qg) ? EXP2F(st[jf][mf][r]) : 0.f;
            }
          } else {
            #pragma unroll
            for (int r = 0; r < 4; ++r) pv[r] = EXP2F(st[jf][mf][r]);
          }
          uint2 w;
          w.x = pk2bf(pv[0], pv[1]);
          w.y = pk2bf(pv[2], pv[3]);
          *(uint2*)&Psm[wave][(mf * 16 + cl) * 40 + jf * 16 + quad * 4] = w;
        }
      }

      bf16x8 vf[4];
      #pragma unroll
      for (int dt = 0; dt < 4; ++dt) {
        const int d = dt * 16 + cl;
        const int slot = ((jl >> 3) + quad) ^ (cl & 7);
        vf[dt] = *(const bf16x8*)&Vsm[cur][d * 64 + slot * 8];
      }

      #pragma unroll
      for (int mf = 0; mf < 2; ++mf) {
        if (mf == 0 && !lowAct) continue;
        const bf16x8 pf = *(const bf16x8*)&Psm[wave][(mf * 16 + cl) * 40 + quad * 8];
        f32x4 z;
        #pragma unroll
        for (int r = 0; r < 4; ++r) z[r] = 0.f;
        const f32x4 ls = MFMA16(pf, ones, z);
        #pragma unroll
        for (int r = 0; r < 4; ++r) lr[mf][r] += ls[r];
        #pragma unroll
        for (int dt = 0; dt < 4; ++dt)
          oacc[mf][dt] = MFMA16(pf, vf[dt], oacc[mf][dt]);
      }
    }
    cur = (cur == 2) ? 0 : cur + 1;
  }

  #pragma unroll
  for (int mf = 0; mf < 2; ++mf) {
    const int qbase = mf ? qhi : qlo;
    float inv[4];
    #pragma unroll
    for (int r = 0; r < 4; ++r) inv[r] = 1.f / lr[mf][r];
    #pragma unroll
    for (int dt = 0; dt < 4; ++dt)
      #pragma unroll
      for (int r = 0; r < 4; ++r)
        CTX[(size_t)(b * 2048 + qbase + quad * 4 + r) * 1024 +
            h * 64 + dt * 16 + cl] = f2bf(oacc[mf][dt][r] * inv[r]);
  }
}

// ---------------------------------------------------------------------------
extern "C" void kernel_launch(void* const* d_in, const int* in_sizes, int n_in,
                              void* d_out, int out_size, void* d_ws, size_t ws_size,
                              hipStream_t stream)
{
  const float* x    = (const float*)d_in[0];
  const float* Wqkv = (const float*)d_in[1];
  const float* Wout = (const float*)d_in[2];
  const float* bout = (const float*)d_in[3];
  float* out = (float*)d_out;

  char* ws = (char*)d_ws;
  unsigned short* xb  = (unsigned short*)(ws);
  unsigned short* wqb = (unsigned short*)(ws + 8388608);
  unsigned short* wob = (unsigned short*)(ws + 14680064);
  unsigned short* Qb  = (unsigned short*)(ws + 16777216);
  unsigned short* Kb  = (unsigned short*)(ws + 25165824);
  unsigned short* Vt  = (unsigned short*)(ws + 33554432);
  unsigned short* CTX = (unsigned short*)(ws + 41943040);

  cast_bf16<<<dim3(8192), dim3(256), 0, stream>>>(x, Wqkv, Wout, xb, wqb, wob);

  // QKV projection: M=4096, N=3072, K=1024 -- 256^2 tile, 192 blocks
  gemm_qkv<<<dim3(192), dim3(512), 0, stream>>>(xb, wqb, Qb, Kb, Vt);

  // Flash attention: 512 uniform blocks (XCD-affine bh), 4 waves each
  attn_mfma<<<dim3(512), dim3(256), 0, stream>>>(Qb, Kb, Vt, CTX);

  // Output projection: M=4096, N=1024, K=1024, + bias
  gemm_bt<0><<<dim3(8, 32), dim3(256), 0, stream>>>(CTX, wob, bout, out, nullptr, nullptr, nullptr);
}

// Round 2
// 185.974 us; speedup vs baseline: 1.0567x; 1.0199x over previous
//
#include <hip/hip_runtime.h>
#include <cstdint>
#include <cstddef>

// MultiHeadAttention R12:
//   R11 structure (256x256-tile 8-wave phase-split QKV GEMM, BK=64, 2-deep
//   LDS dbuf, 4 phases/K-tile, ONE counted vmcnt(4)/K-tile, setprio around
//   MFMA clusters) with the LDS swizzle FIXED: full 3-bit XOR
//   (phys_slot = logical_slot ^ (row&7)), same involution as the proven
//   attn_mfma K/V staging. R11's 1-bit swizzle left quads 0/2 and 1/3
//   aliased on the same bank groups -> 2.46M bank-conflict cycles.
//   cast -> gemm_qkv -> attn_mfma (unchanged) -> gemm_bt<0> out-proj.
// ws layout (bytes):
//   xb @0 [4096][1024] bf16 | wqb @8388608 [3072][1024] | wob @14680064 [1024][1024]
//   Qb @16777216, Kb @25165824: [2][16][2048][64] bf16 (Qb = Q*log2e)
//   Vt @33554432: [2][16][64][2048] bf16 (transposed)
//   CTX @41943040 [4096][1024] bf16
// MFMA 16x16x32_bf16 frags: A[m=lane&15][k=quad*8+i], B[n=lane&15][k=quad*8+i],
// C/D[row=quad*4+reg][col=lane&15]. Swapped operands -> D = C^T.

typedef __attribute__((ext_vector_type(8))) short bf16x8;
typedef __attribute__((ext_vector_type(4))) float f32x4;

#define LOG2E 1.44269504f

#define MFMA16(a, b, c) __builtin_amdgcn_mfma_f32_16x16x32_bf16((a), (b), (c), 0, 0, 0)

#define GLDS16(g, s)                                                        \
  __builtin_amdgcn_global_load_lds(                                         \
      (const __attribute__((address_space(1))) void*)(g),                   \
      (__attribute__((address_space(3))) void*)(s), 16, 0, 0)

// Manual barrier: wait until <= N vector-memory ops outstanding, then barrier.
// ONLY valid when the loop's vmem traffic is exclusively the staged GLDS.
#define ASYNC_BAR(N) asm volatile("s_waitcnt vmcnt(" #N ")\n\ts_barrier" ::: "memory")
#define BAR() asm volatile("s_barrier" ::: "memory")

#if __has_builtin(__builtin_amdgcn_exp2f)
#define EXP2F(x) __builtin_amdgcn_exp2f(x)
#else
#define EXP2F(x) exp2f(x)
#endif

static __device__ __forceinline__ unsigned short f2bf(float f) {  // RNE
  unsigned int u = __builtin_bit_cast(unsigned int, f);
  u += 0x7FFFu + ((u >> 16) & 1u);
  return (unsigned short)(u >> 16);
}

// pack two fp32 -> two bf16 (round-nearest) in one u32: 2 add + 1 perm
static __device__ __forceinline__ unsigned int pk2bf(float a, float b) {
  const unsigned int ua = __builtin_bit_cast(unsigned int, a) + 0x8000u;
  const unsigned int ub = __builtin_bit_cast(unsigned int, b) + 0x8000u;
  return __builtin_amdgcn_perm(ub, ua, 0x07060302);
}

// ---------------------------------------------------------------------------
__global__ __launch_bounds__(256) void cast_bf16(const float* __restrict__ x,
                                                 const float* __restrict__ wq,
                                                 const float* __restrict__ wo,
                                                 unsigned short* __restrict__ xb,
                                                 unsigned short* __restrict__ wqb,
                                                 unsigned short* __restrict__ wob)
{
  const int id = blockIdx.x * 256 + threadIdx.x;
  const float* src;
  unsigned short* dst;
  int off;
  if (id < 1048576)               { src = x;  dst = xb;  off = id; }
  else if (id < 1048576 + 786432) { src = wq; dst = wqb; off = id - 1048576; }
  else                            { src = wo; dst = wob; off = id - (1048576 + 786432); }
  float4 v = ((const float4*)src)[off];
  ushort4 o;
  o.x = f2bf(v.x); o.y = f2bf(v.y); o.z = f2bf(v.z); o.w = f2bf(v.w);
  ((ushort4*)dst)[off] = o;
}

// ---------------------------------------------------------------------------
// QKV GEMM R12: 256x256 tile, BK=64, 512 threads = 8 waves (2M x 4N),
// per-wave 128x64 output (acc[8][4] of 16x16 frags).
// LDS 128 KiB: 2 buffers x (A 256x64 | B 256x64) bf16, rows of 128B split
// into 8x16B slots, phys_slot = logical_slot ^ (row & 7)   [FULL 3-bit XOR].
// global_load_lds writes linearly -> the GLOBAL source is pre-swizzled with
// the same involution (row&7 == lane>>3 inside each 8-row stripe); ds_reads
// apply slot ^ (cl&7) (fragment row bases are multiples of 16).
// Conflict check: per (mt,kk) read, each of 8 slot-groups gets exactly 8
// lanes -> every bank services 8 dwords -> 8-cycle wave64 b128 minimum.
// 4 phases per K-tile (quadrants: (msub,nsub) = 00,01,11,10), 16 MFMA each.
// Staging: 1 half-tile (2 GLDS/thread) per phase, 1.25 tiles ahead:
//   t-P0: B-hi(t+1) | t-P1: A-hi(t+1) | t-P2: B-lo(t+2) | t-P3: A-lo(t+2)
// ONE vmcnt(4) per K-tile (at P0) -- loads never drained in-loop.
// Barriers at P0 (with vmcnt), P2, P3; P0->P1 needs none (disjoint buffers).
// ---------------------------------------------------------------------------
#define MMAC(AF, BF, MS, NS)                                                       \
  do {                                                                             \
    __builtin_amdgcn_s_setprio(1);                                                 \
    if (swapped) {                                                                 \
      _Pragma("unroll")                                                            \
      for (int mt = 0; mt < 4; ++mt)                                               \
        _Pragma("unroll")                                                          \
        for (int nt = 0; nt < 2; ++nt) {                                           \
          acc[(MS)*4+mt][(NS)*2+nt] = MFMA16(BF[nt][0], AF[mt][0], acc[(MS)*4+mt][(NS)*2+nt]); \
          acc[(MS)*4+mt][(NS)*2+nt] = MFMA16(BF[nt][1], AF[mt][1], acc[(MS)*4+mt][(NS)*2+nt]); \
        }                                                                          \
    } else {                                                                       \
      _Pragma("unroll")                                                            \
      for (int mt = 0; mt < 4; ++mt)                                               \
        _Pragma("unroll")                                                          \
        for (int nt = 0; nt < 2; ++nt) {                                           \
          acc[(MS)*4+mt][(NS)*2+nt] = MFMA16(AF[mt][0], BF[nt][0], acc[(MS)*4+mt][(NS)*2+nt]); \
          acc[(MS)*4+mt][(NS)*2+nt] = MFMA16(AF[mt][1], BF[nt][1], acc[(MS)*4+mt][(NS)*2+nt]); \
        }                                                                          \
    }                                                                              \
    __builtin_amdgcn_s_setprio(0);                                                 \
  } while (0)

__global__ __launch_bounds__(512, 2) void gemm_qkv(const unsigned short* __restrict__ A,
                                                   const unsigned short* __restrict__ B,
                                                   unsigned short* __restrict__ Qb,
                                                   unsigned short* __restrict__ Kb,
                                                   unsigned short* __restrict__ Vt)
{
  // shorts: buf b: A @ b*32768 (256 rows x 64), B @ b*32768+16384. 128 KiB.
  __shared__ unsigned short pool[65536];

  const int tid  = threadIdx.x;
  const int wave = tid >> 6, lane = tid & 63, quad = lane >> 4, cl = lane & 15;
  const int wm = wave >> 2, wn = wave & 3;

  // Bijective XCD chunking: 192 blocks, 24/XCD covering a 4(mb) x 6(nb) chunk.
  const int bid = blockIdx.x;
  const int xcd = bid & 7, j = bid >> 3;
  const int mb = (xcd >> 1) * 4 + j / 6;
  const int nb = (xcd & 1) * 6 + j % 6;
  const int m0 = mb * 256, n0 = nb * 256;
  const int part = nb >> 2;                 // 0=Q 1=K 2=V
  const bool swapped = (part < 2);

  // --- staging: per GLDS16, wave covers 8 rows x 128B linearly.
  // lane l -> row r0+(l>>3), phys slot l&7. Pre-swizzled global source:
  // logical slot = phys ^ (row&7) = (l&7) ^ (l>>3)   [r0 is a multiple of 8]
  const int lrow = lane >> 3;
  const int sg   = (lane & 7) ^ lrow;

  auto stageA = [&](int h0, int buf, int k0) {
    #pragma unroll
    for (int ii = 0; ii < 2; ++ii) {
      const int r0 = h0 + wave * 16 + ii * 8;
      GLDS16(A + (size_t)(m0 + r0 + lrow) * 1024 + k0 + sg * 8,
             &pool[buf * 32768 + r0 * 64]);
    }
  };
  auto stageB = [&](int h0, int buf, int k0) {
    #pragma unroll
    for (int ii = 0; ii < 2; ++ii) {
      const int r0 = h0 + wave * 16 + ii * 8;
      GLDS16(B + (size_t)(n0 + r0 + lrow) * 1024 + k0 + sg * 8,
             &pool[buf * 32768 + 16384 + r0 * 64]);
    }
  };

  // --- fragment reads: row = 16-aligned base + cl -> row&7 == cl&7.
  // logical k-chunk (kk*4+quad) lives at phys slot (kk*4+quad) ^ (cl&7).
  const int rswz = cl & 7;
  auto loadA = [&](bf16x8 (&af)[4][2], int msub, int b) {
    const unsigned short* base = &pool[b * 32768];
    #pragma unroll
    for (int mt = 0; mt < 4; ++mt) {
      const int row = wm * 128 + msub * 64 + mt * 16 + cl;
      #pragma unroll
      for (int kk = 0; kk < 2; ++kk)
        af[mt][kk] = *(const bf16x8*)&base[row * 64 + ((kk * 4 + quad) ^ rswz) * 8];
    }
  };
  auto loadB = [&](bf16x8 (&bf)[2][2], int nsub, int b) {
    const unsigned short* base = &pool[b * 32768 + 16384];
    #pragma unroll
    for (int nt = 0; nt < 2; ++nt) {
      const int row = wn * 64 + nsub * 32 + nt * 16 + cl;
      #pragma unroll
      for (int kk = 0; kk < 2; ++kk)
        bf[nt][kk] = *(const bf16x8*)&base[row * 64 + ((kk * 4 + quad) ^ rswz) * 8];
    }
  };

  f32x4 acc[8][4];
  #pragma unroll
  for (int i = 0; i < 8; ++i)
    #pragma unroll
    for (int jj = 0; jj < 4; ++jj)
      #pragma unroll
      for (int r = 0; r < 4; ++r) acc[i][jj][r] = 0.f;

  // Prologue: all 4 half-tiles of tile0, then lo halves of tile1 (12 loads).
  stageB(0,   0, 0);
  stageA(0,   0, 0);
  stageB(128, 0, 0);
  stageA(128, 0, 0);
  stageB(0,   1, 64);
  stageA(0,   1, 64);

  #pragma unroll 1
  for (int t = 0; t < 16; ++t) {
    const int b = t & 1, bn = b ^ 1;
    const int kc  = (t + 1) * 64;
    const int kc2 = (t + 2) * 64;

    bf16x8 af[4][2], bfA[2][2], bfB[2][2];

    // P0: quadrant (0,0). vmcnt(4): guarantees all 4 halves of tile t
    // (newest needed = A-hi(t) @ (t-1)-P1; newer in flight = B-lo/A-lo(t+1)).
    if (t < 15) { ASYNC_BAR(4); } else { ASYNC_BAR(0); }
    loadA(af, 0, b);
    loadB(bfA, 0, b);
    if (t < 15) stageB(128, bn, kc);       // B-hi(t+1)
    MMAC(af, bfA, 0, 0);

    // P1: quadrant (0,1). No barrier needed: reads tile-t B (published at P0),
    // GLDS writes buffer bn (not being read).
    loadB(bfB, 1, b);
    if (t < 15) stageA(128, bn, kc);       // A-hi(t+1)
    MMAC(af, bfB, 0, 1);

    // P2: quadrant (1,1). Barrier: B-lo(t+2) overwrites B-lo(b) whose last
    // reads were P1 (other waves).
    BAR();
    loadA(af, 1, b);
    if (t < 14) stageB(0, b, kc2);         // B-lo(t+2)
    MMAC(af, bfB, 1, 1);

    // P3: quadrant (1,0), reuses bfA regs. Barrier: A-lo(t+2) overwrites
    // A-lo(b) whose last reads were P2 (wm=0 waves).
    BAR();
    if (t < 14) stageA(0, b, kc2);         // A-lo(t+2)
    MMAC(af, bfA, 1, 0);
  }
  // ASYNC_BAR(0) at t=15-P0 drained all staging: no GLDS in flight here.

  const int bb = m0 >> 11, ss = m0 & 2047;
  if (part < 2) {
    // Q/K (swapped: D=C^T): lane holds 4 consecutive d for one s -> ushort4
    unsigned short* dst = (part == 0) ? Qb : Kb;
    const float sc2 = (part == 0) ? LOG2E : 1.0f;
    const int npb = (n0 & 1023) + wn * 64;
    #pragma unroll
    for (int mt = 0; mt < 8; ++mt) {
      const int m = ss + wm * 128 + mt * 16 + cl;
      #pragma unroll
      for (int nt = 0; nt < 4; ++nt) {
        const int np = npb + nt * 16 + quad * 4;
        const int hh = np >> 6, d0 = np & 63;
        ushort4 pk;
        pk.x = f2bf(acc[mt][nt][0] * sc2);
        pk.y = f2bf(acc[mt][nt][1] * sc2);
        pk.z = f2bf(acc[mt][nt][2] * sc2);
        pk.w = f2bf(acc[mt][nt][3] * sc2);
        *(ushort4*)&dst[((size_t)(bb * 16 + hh) * 2048 + m) * 64 + d0] = pk;
      }
    }
  } else {
    // V (normal orientation): transpose through LDS (reuse pool),
    // trans[128][264] shorts per round; 2 rounds (wn pairs).
    unsigned short* trans = pool;
    #pragma unroll 1
    for (int r = 0; r < 2; ++r) {
      __syncthreads();
      if ((wn >> 1) == r) {
        #pragma unroll
        for (int mt = 0; mt < 8; ++mt) {
          const int s_l = wm * 128 + mt * 16 + quad * 4;
          #pragma unroll
          for (int nt = 0; nt < 4; ++nt) {
            const int n_l = (wn & 1) * 64 + nt * 16 + cl;
            ushort4 pk;
            pk.x = f2bf(acc[mt][nt][0]); pk.y = f2bf(acc[mt][nt][1]);
            pk.z = f2bf(acc[mt][nt][2]); pk.w = f2bf(acc[mt][nt][3]);
            *(ushort4*)&trans[n_l * 264 + s_l] = pk;
          }
        }
      }
      __syncthreads();
      const int row = tid >> 2, q4 = tid & 3;
      const int nv = (n0 & 1023) + r * 128 + row;
      const int hh = nv >> 6, d = nv & 63;
      unsigned short* drow = Vt + ((size_t)(bb * 16 + hh) * 64 + d) * 2048 + ss + q4 * 64;
      #pragma unroll
      for (int i = 0; i < 8; ++i)
        *(bf16x8*)(drow + i * 8) = *(const bf16x8*)&trans[row * 264 + q4 * 64 + i * 8];
    }
  }
}

// ---------------------------------------------------------------------------
// MFMA GEMM, TRIPLE-buffered K-loop, manual barriers (prefetch distance 2).
// Retained for the out-projection (MODE 0) only.
// ---------------------------------------------------------------------------
template <int MODE>
__global__ __launch_bounds__(256) void gemm_bt(const unsigned short* __restrict__ A,
                                               const unsigned short* __restrict__ B,
                                               const float* __restrict__ bias,
                                               float* __restrict__ OutF,
                                               unsigned short* __restrict__ Qb,
                                               unsigned short* __restrict__ Kb,
                                               unsigned short* __restrict__ Vt)
{
  __shared__ unsigned short pool[24576];   // 3 stages x (A 4096 | B 4096) shorts

  const int tid  = threadIdx.x;
  const int wave = tid >> 6, lane = tid & 63, quad = lane >> 4, cl = lane & 15;
  const int wm = wave >> 1, wn = wave & 1;
  const int m0 = blockIdx.y * 128, n0 = blockIdx.x * 128;
  const int sr = lane >> 2, sc = lane & 3;

  const int part = (MODE == 1) ? (n0 >> 10) : 0;     // 0=Q 1=K 2=V
  const bool swapped = (MODE == 0) || (part < 2);

  f32x4 acc[4][4];
  #pragma unroll
  for (int i = 0; i < 4; ++i)
    #pragma unroll
    for (int j = 0; j < 4; ++j)
      #pragma unroll
      for (int r = 0; r < 4; ++r) acc[i][j][r] = 0.f;

  const int scs = (sc ^ ((sr >> 1) & 3)) * 8;
  const int rchunk = (quad ^ ((cl >> 1) & 3)) * 8;

  auto stage = [&](int k0, int buf) {
    unsigned short* As = pool + buf * 8192;
    unsigned short* Bs = As + 4096;
    #pragma unroll
    for (int ii = 0; ii < 2; ++ii) {
      const int r = wave * 32 + ii * 16 + sr;
      GLDS16(A + (size_t)(m0 + r) * 1024 + k0 + scs, &As[(wave * 32 + ii * 16) * 32]);
      GLDS16(B + (size_t)(n0 + r) * 1024 + k0 + scs, &Bs[(wave * 32 + ii * 16) * 32]);
    }
  };

  stage(0, 0);
  stage(32, 1);
  int cur = 0;
  #pragma unroll 1
  for (int it = 0; it < 32; ++it) {
    if (it + 2 < 32) {
      ASYNC_BAR(4);                              // drain stage(it); keep stage(it+1)
      const int bnx = (cur == 0) ? 2 : cur - 1;  // (cur+2)%3
      stage((it + 2) * 32, bnx);
    } else if (it + 1 < 32) {
      ASYNC_BAR(4);
    } else {
      ASYNC_BAR(0);
    }

    const unsigned short* As = pool + cur * 8192;
    const unsigned short* Bs = As + 4096;
    bf16x8 af[4], bfr[4];
    #pragma unroll
    for (int mt = 0; mt < 4; ++mt)
      af[mt] = *(const bf16x8*)&As[(wm * 64 + mt * 16 + cl) * 32 + rchunk];
    #pragma unroll
    for (int nt = 0; nt < 4; ++nt)
      bfr[nt] = *(const bf16x8*)&Bs[(wn * 64 + nt * 16 + cl) * 32 + rchunk];

    if (swapped) {
      #pragma unroll
      for (int mt = 0; mt < 4; ++mt)
        #pragma unroll
        for (int nt = 0; nt < 4; ++nt)
          acc[mt][nt] = MFMA16(bfr[nt], af[mt], acc[mt][nt]);   // D = C^T
    } else {
      #pragma unroll
      for (int mt = 0; mt < 4; ++mt)
        #pragma unroll
        for (int nt = 0; nt < 4; ++nt)
          acc[mt][nt] = MFMA16(af[mt], bfr[nt], acc[mt][nt]);
    }
    cur = (cur == 2) ? 0 : cur + 1;
  }

  if (MODE == 1) {
    const int bb = m0 >> 11, ss = m0 & 2047;
    if (part == 2) {
      // V (normal orientation): transpose through LDS, coalesced Vt row stores
      #pragma unroll
      for (int half = 0; half < 2; ++half) {
        __syncthreads();
        if (wn == half) {
          #pragma unroll
          for (int mt = 0; mt < 4; ++mt)
            #pragma unroll
            for (int nt = 0; nt < 4; ++nt) {
              const int nl = nt * 16 + cl;
              const int ml = wm * 64 + mt * 16 + quad * 4;
              ushort4 pk;
              pk.x = f2bf(acc[mt][nt][0]); pk.y = f2bf(acc[mt][nt][1]);
              pk.z = f2bf(acc[mt][nt][2]); pk.w = f2bf(acc[mt][nt][3]);
              *(ushort4*)&pool[nl * 136 + ml] = pk;
            }
        }
        __syncthreads();
        const int row = tid >> 2, q4 = tid & 3;
        const int nglob = n0 + half * 64 + row;
        const int hh = (nglob >> 6) & 15, d = nglob & 63;
        unsigned short* drow = Vt + ((size_t)(bb * 16 + hh) * 64 + d) * 2048 + ss;
        #pragma unroll
        for (int i = 0; i < 4; ++i) {
          const bf16x8 v = *(const bf16x8*)&pool[row * 136 + q4 * 32 + i * 8];
          *(bf16x8*)(drow + q4 * 32 + i * 8) = v;
        }
      }
    } else {
      // Q/K (swapped: D=C^T): lane holds 4 consecutive d for one s -> ushort4
      unsigned short* dst = (part == 0) ? Qb : Kb;
      const float sc2 = (part == 0) ? LOG2E : 1.0f;
      #pragma unroll
      for (int mt = 0; mt < 4; ++mt) {
        const int m = ss + wm * 64 + mt * 16 + cl;
        #pragma unroll
        for (int nt = 0; nt < 4; ++nt) {
          const int np = (n0 & 1023) + wn * 64 + nt * 16 + quad * 4;
          const int hh = np >> 6, d0 = np & 63;
          ushort4 pk;
          pk.x = f2bf(acc[mt][nt][0] * sc2);
          pk.y = f2bf(acc[mt][nt][1] * sc2);
          pk.z = f2bf(acc[mt][nt][2] * sc2);
          pk.w = f2bf(acc[mt][nt][3] * sc2);
          *(ushort4*)&dst[((size_t)(bb * 16 + hh) * 2048 + m) * 64 + d0] = pk;
        }
      }
    }
  } else {
    #pragma unroll
    for (int mt = 0; mt < 4; ++mt) {
      const int m = m0 + wm * 64 + mt * 16 + cl;
      #pragma unroll
      for (int nt = 0; nt < 4; ++nt) {
        const int n = n0 + wn * 64 + nt * 16 + quad * 4;
        const float4 bv = *(const float4*)(bias + n);
        float4 o;
        o.x = acc[mt][nt][0] + bv.x; o.y = acc[mt][nt][1] + bv.y;
        o.z = acc[mt][nt][2] + bv.z; o.w = acc[mt][nt][3] + bv.w;
        *(float4*)&OutF[(size_t)m * 1024 + n] = o;
      }
    }
  }
}

// ---------------------------------------------------------------------------
// Flash attention (unchanged): K AND V staged in LDS via GLDS with
// triple-buffered staging + manual vmcnt(4) barriers. Uniform blocks (wave
// owns low group g and high 127-g); no-max softmax P = 2^(q·k·log2e).
// ---------------------------------------------------------------------------
__global__ __launch_bounds__(256) void attn_mfma(const unsigned short* __restrict__ Qb,
                                                 const unsigned short* __restrict__ Kb,
                                                 const unsigned short* __restrict__ Vt,
                                                 unsigned short* __restrict__ CTX)
{
  __shared__ unsigned short Ksm[3][64 * 64];
  __shared__ unsigned short Vsm[3][64 * 64];
  __shared__ unsigned short Psm[4][32 * 40];

  const int tid  = threadIdx.x;
  const int wave = tid >> 6, lane = tid & 63, quad = lane >> 4, cl = lane & 15;

  const int L  = blockIdx.x;
  const int bh = 4 * (L & 7) + ((L >> 3) & 3);    // XCD-affine: 4 bh per XCD
  const int b  = bh >> 4, h = bh & 15;
  const int p  = L >> 5;                          // 0..15
  const int g  = p * 4 + wave;                    // low group 0..63
  const int qlo = g * 16;
  const int qhi = (127 - g) * 16;
  const size_t base = (size_t)bh * (2048 * 64);

  bf16x8 qf[2][2];
  #pragma unroll
  for (int dk = 0; dk < 2; ++dk) {
    qf[0][dk] = *(const bf16x8*)(Qb + base + (size_t)(qlo + cl) * 64 + dk * 32 + quad * 8);
    qf[1][dk] = *(const bf16x8*)(Qb + base + (size_t)(qhi + cl) * 64 + dk * 32 + quad * 8);
  }

  f32x4 oacc[2][4];
  #pragma unroll
  for (int mf = 0; mf < 2; ++mf)
    #pragma unroll
    for (int dt = 0; dt < 4; ++dt)
      #pragma unroll
      for (int r = 0; r < 4; ++r) oacc[mf][dt][r] = 0.f;
  float lr[2][4] = {};

  bf16x8 ones;
  #pragma unroll
  for (int k = 0; k < 8; ++k) ones[k] = (short)0x3F80;

  const int lrow  = lane >> 3;
  const int lslot = (lane & 7) ^ lrow;
  const int nch = 32 - p;                          // >= 17

  auto stageKV = [&](int j64, int buf) {
    #pragma unroll
    for (int ii = 0; ii < 2; ++ii) {
      const int r0 = wave * 16 + ii * 8;
      GLDS16(Kb + base + (size_t)(j64 + r0 + lrow) * 64 + lslot * 8, &Ksm[buf][r0 * 64]);
      GLDS16(Vt + base + (size_t)(r0 + lrow) * 2048 + j64 + lslot * 8, &Vsm[buf][r0 * 64]);
    }
  };

  stageKV(0, 0);
  stageKV(64, 1);
  int cur = 0;
  #pragma unroll 1
  for (int ch = 0; ch < nch; ++ch) {
    if (ch + 2 < nch) {
      ASYNC_BAR(4);                              // drain stage(ch); keep stage(ch+1)
      const int bnx = (cur == 0) ? 2 : cur - 1;
      stageKV((ch + 2) * 64, bnx);
    } else if (ch + 1 < nch) {
      ASYNC_BAR(4);
    } else {
      ASYNC_BAR(0);
    }

    const int j64 = ch * 64;
    #pragma unroll
    for (int jli = 0; jli < 2; ++jli) {
      const int jg0 = j64 + jli * 32;
      if (jg0 > qhi + 15) continue;
      const bool lowAct = (jg0 <= qlo + 15);
      const int jl = jli * 32;

      bf16x8 kf[2][2];
      #pragma unroll
      for (int jf = 0; jf < 2; ++jf)
        #pragma unroll
        for (int dk = 0; dk < 2; ++dk) {
          const int jrow = jl + jf * 16 + cl;
          const int slot = (dk * 4 + quad) ^ (cl & 7);
          kf[jf][dk] = *(const bf16x8*)&Ksm[cur][jrow * 64 + slot * 8];
        }

      f32x4 st[2][2];
      #pragma unroll
      for (int jf = 0; jf < 2; ++jf)
        #pragma unroll
        for (int mf = 0; mf < 2; ++mf) {
          if (mf == 0 && !lowAct) continue;
          f32x4 z;
          #pragma unroll
          for (int r = 0; r < 4; ++r) z[r] = 0.f;
          z = MFMA16(kf[jf][0], qf[mf][0], z);
          st[jf][mf] = MFMA16(kf[jf][1], qf[mf][1], z);
        }

      #pragma unroll
      for (int mf = 0; mf < 2; ++mf) {
        if (mf == 0 && !lowAct) continue;
        const int qbase = mf ? qhi : qlo;
        const bool diag = (jg0 + 32 > qbase);
        #pragma unroll
        for (int jf = 0; jf < 2; ++jf) {
          float pv[4];
          if (diag) {
            const int qg = qbase + cl;
            #pragma unroll
            for (int r = 0; r < 4; ++r) {
              const int jg = jg0 + jf * 16 + quad * 4 + r;
              pv[r] = (jg <= qg) ? EXP2F(st[jf][mf][r]) : 0.f;
            }
          } else {
            #pragma unroll
            for (int r = 0; r < 4; ++r) pv[r] = EXP2F(st[jf][mf][r]);
          }
          uint2 w;
          w.x = pk2bf(pv[0], pv[1]);
          w.y = pk2bf(pv[2], pv[3]);
          *(uint2*)&Psm[wave][(mf * 16 + cl) * 40 + jf * 16 + quad * 4] = w;
        }
      }

      bf16x8 vf[4];
      #pragma unroll
      for (int dt = 0; dt < 4; ++dt) {
        const int d = dt * 16 + cl;
        const int slot = ((jl >> 3) + quad) ^ (cl & 7);
        vf[dt] = *(const bf16x8*)&Vsm[cur][d * 64 + slot * 8];
      }

      #pragma unroll
      for (int mf = 0; mf < 2; ++mf) {
        if (mf == 0 && !lowAct) continue;
        const bf16x8 pf = *(const bf16x8*)&Psm[wave][(mf * 16 + cl) * 40 + quad * 8];
        f32x4 z;
        #pragma unroll
        for (int r = 0; r < 4; ++r) z[r] = 0.f;
        const f32x4 ls = MFMA16(pf, ones, z);
        #pragma unroll
        for (int r = 0; r < 4; ++r) lr[mf][r] += ls[r];
        #pragma unroll
        for (int dt = 0; dt < 4; ++dt)
          oacc[mf][dt] = MFMA16(pf, vf[dt], oacc[mf][dt]);
      }
    }
    cur = (cur == 2) ? 0 : cur + 1;
  }

  #pragma unroll
  for (int mf = 0; mf < 2; ++mf) {
    const int qbase = mf ? qhi : qlo;
    float inv[4];
    #pragma unroll
    for (int r = 0; r < 4; ++r) inv[r] = 1.f / lr[mf][r];
    #pragma unroll
    for (int dt = 0; dt < 4; ++dt)
      #pragma unroll
      for (int r = 0; r < 4; ++r)
        CTX[(size_t)(b * 2048 + qbase + quad * 4 + r) * 1024 +
            h * 64 + dt * 16 + cl] = f2bf(oacc[mf][dt][r] * inv[r]);
  }
}

// ---------------------------------------------------------------------------
extern "C" void kernel_launch(void* const* d_in, const int* in_sizes, int n_in,
                              void* d_out, int out_size, void* d_ws, size_t ws_size,
                              hipStream_t stream)
{
  const float* x    = (const float*)d_in[0];
  const float* Wqkv = (const float*)d_in[1];
  const float* Wout = (const float*)d_in[2];
  const float* bout = (const float*)d_in[3];
  float* out = (float*)d_out;

  char* ws = (char*)d_ws;
  unsigned short* xb  = (unsigned short*)(ws);
  unsigned short* wqb = (unsigned short*)(ws + 8388608);
  unsigned short* wob = (unsigned short*)(ws + 14680064);
  unsigned short* Qb  = (unsigned short*)(ws + 16777216);
  unsigned short* Kb  = (unsigned short*)(ws + 25165824);
  unsigned short* Vt  = (unsigned short*)(ws + 33554432);
  unsigned short* CTX = (unsigned short*)(ws + 41943040);

  cast_bf16<<<dim3(8192), dim3(256), 0, stream>>>(x, Wqkv, Wout, xb, wqb, wob);

  // QKV projection: M=4096, N=3072, K=1024 -- 256^2 tile, 192 blocks
  gemm_qkv<<<dim3(192), dim3(512), 0, stream>>>(xb, wqb, Qb, Kb, Vt);

  // Flash attention: 512 uniform blocks (XCD-affine bh), 4 waves each
  attn_mfma<<<dim3(512), dim3(256), 0, stream>>>(Qb, Kb, Vt, CTX);

  // Output projection: M=4096, N=1024, K=1024, + bias
  gemm_bt<0><<<dim3(8, 32), dim3(256), 0, stream>>>(CTX, wob, bout, out, nullptr, nullptr, nullptr);
}